// Round 1
// baseline (1920.312 us; speedup 1.0000x reference)
//
#include <hip/hip_runtime.h>

// APPNP: h = relu(x@W0+b0)@W1+b1 ; z0=h ; z_{k+1} = 0.9 * (Ahat z_k) + 0.1 * h  (10 iters)
// Ahat = D^-1/2 (A + I) D^-1/2 with deg over source(row) incl. self-loop weight 1.

#define LDW 68  // LDS leading-dim pad: 68 mod 32 = 4 -> max 2-way bank aliasing (free)

__global__ __launch_bounds__(256) void k_init_deg(float* __restrict__ deg, int N) {
    int i = blockIdx.x * 256 + threadIdx.x;
    if (i < N) deg[i] = 1.0f;  // self-loop weight
}

__global__ __launch_bounds__(256) void k_deg_cnt(const int* __restrict__ row, const int* __restrict__ col,
                                                 const float* __restrict__ ew, float* __restrict__ deg,
                                                 int* __restrict__ cnt, int E) {
    int e = blockIdx.x * 256 + threadIdx.x;
    if (e < E) {
        atomicAdd(&deg[row[e]], ew[e]);   // out-degree by source
        atomicAdd(&cnt[col[e]], 1);       // in-degree histogram for CSR-by-dest
    }
}

__global__ __launch_bounds__(256) void k_rsqrt(float* __restrict__ d, int N) {
    int i = blockIdx.x * 256 + threadIdx.x;
    if (i < N) { float v = d[i]; d[i] = v > 0.f ? rsqrtf(v) : 0.f; }
}

// ---- 3-kernel exclusive scan of cnt[N] -> rowp[N], chunk = 1024 ----
__global__ __launch_bounds__(256) void k_scanA(const int* __restrict__ cnt, int* __restrict__ csum, int N) {
    __shared__ int s[256];
    int t = threadIdx.x, base = blockIdx.x * 1024;
    int p = 0;
#pragma unroll
    for (int j = 0; j < 4; ++j) { int idx = base + t + 256 * j; if (idx < N) p += cnt[idx]; }
    s[t] = p; __syncthreads();
    for (int off = 128; off > 0; off >>= 1) { if (t < off) s[t] += s[t + off]; __syncthreads(); }
    if (t == 0) csum[blockIdx.x] = s[0];
}

__global__ __launch_bounds__(256) void k_scanB(int* __restrict__ csum, int NC) {
    __shared__ int s[256];
    int t = threadIdx.x;
    int v = (t < NC) ? csum[t] : 0;
    s[t] = v; __syncthreads();
    for (int off = 1; off < 256; off <<= 1) {
        int x = (t >= off) ? s[t - off] : 0;
        __syncthreads();
        s[t] += x; __syncthreads();
    }
    if (t < NC) csum[t] = s[t] - v;  // exclusive
}

__global__ __launch_bounds__(256) void k_scanC(const int* __restrict__ cnt, const int* __restrict__ csum,
                                               int* __restrict__ rowp, int N) {
    __shared__ int s[256];
    int t = threadIdx.x, base = blockIdx.x * 1024 + t * 4;
    int c0 = (base + 0 < N) ? cnt[base + 0] : 0;
    int c1 = (base + 1 < N) ? cnt[base + 1] : 0;
    int c2 = (base + 2 < N) ? cnt[base + 2] : 0;
    int c3 = (base + 3 < N) ? cnt[base + 3] : 0;
    int ts = c0 + c1 + c2 + c3;
    s[t] = ts; __syncthreads();
    for (int off = 1; off < 256; off <<= 1) {
        int x = (t >= off) ? s[t - off] : 0;
        __syncthreads();
        s[t] += x; __syncthreads();
    }
    int o = csum[blockIdx.x] + s[t] - ts;
    if (base + 0 < N) rowp[base + 0] = o;
    if (base + 1 < N) rowp[base + 1] = o + c0;
    if (base + 2 < N) rowp[base + 2] = o + c0 + c1;
    if (base + 3 < N) rowp[base + 3] = o + c0 + c1 + c2;
}

__global__ __launch_bounds__(256) void k_scatter(const int* __restrict__ row, const int* __restrict__ col,
                                                 const float* __restrict__ ew, const float* __restrict__ dinv,
                                                 const int* __restrict__ rowp, int* __restrict__ cursor,
                                                 int2* __restrict__ srcw, int E) {
    int e = blockIdx.x * 256 + threadIdx.x;
    if (e < E) {
        int c = col[e], r = row[e];
        int pos = rowp[c] + atomicAdd(&cursor[c], 1);
        float w = dinv[r] * ew[e] * dinv[c];
        srcw[pos] = make_int2(r, __float_as_int(w));
    }
}

// ---- fused 2-layer MLP: 64 rows x 64 cols per block, 4x4 register tile per thread ----
__global__ __launch_bounds__(256) void k_mlp(const float* __restrict__ x,
                                             const float* __restrict__ W0, const float* __restrict__ b0,
                                             const float* __restrict__ W1, const float* __restrict__ b1,
                                             float* __restrict__ h, int N) {
    __shared__ __align__(16) float xs[64 * LDW];  // xT[k][r] (layer1) / hT[c][r] (layer2)
    __shared__ __align__(16) float ws[64 * LDW];  // W0 chunk / W1  [k][c]
    int tid = threadIdx.x;
    int tc = tid & 15, tr = tid >> 4;            // 16x16 threads, 4x4 outputs each
    int rbase = blockIdx.x * 64;

    float acc[4][4];
#pragma unroll
    for (int i = 0; i < 4; ++i)
#pragma unroll
        for (int j = 0; j < 4; ++j) acc[i][j] = 0.f;

    for (int ck = 0; ck < 8; ++ck) {
        int k0 = ck * 64;
#pragma unroll
        for (int j = 0; j < 4; ++j) {  // stage x chunk transposed
            int l = tid + 256 * j;
            int r = l >> 4, kq = l & 15;
            int gr = rbase + r;
            float4 v = make_float4(0.f, 0.f, 0.f, 0.f);
            if (gr < N) v = *(const float4*)(x + (size_t)gr * 512 + k0 + kq * 4);
            xs[(kq * 4 + 0) * LDW + r] = v.x;
            xs[(kq * 4 + 1) * LDW + r] = v.y;
            xs[(kq * 4 + 2) * LDW + r] = v.z;
            xs[(kq * 4 + 3) * LDW + r] = v.w;
        }
#pragma unroll
        for (int j = 0; j < 4; ++j) {  // stage W0 chunk [k][c]
            int l = tid + 256 * j;
            int kk = l >> 4, cq = l & 15;
            *(float4*)(ws + kk * LDW + cq * 4) = *(const float4*)(W0 + (size_t)(k0 + kk) * 64 + cq * 4);
        }
        __syncthreads();
#pragma unroll 4
        for (int k = 0; k < 64; ++k) {
            float4 a = *(const float4*)(xs + k * LDW + tr * 4);
            float4 w = *(const float4*)(ws + k * LDW + tc * 4);
            acc[0][0] = fmaf(a.x, w.x, acc[0][0]); acc[0][1] = fmaf(a.x, w.y, acc[0][1]);
            acc[0][2] = fmaf(a.x, w.z, acc[0][2]); acc[0][3] = fmaf(a.x, w.w, acc[0][3]);
            acc[1][0] = fmaf(a.y, w.x, acc[1][0]); acc[1][1] = fmaf(a.y, w.y, acc[1][1]);
            acc[1][2] = fmaf(a.y, w.z, acc[1][2]); acc[1][3] = fmaf(a.y, w.w, acc[1][3]);
            acc[2][0] = fmaf(a.z, w.x, acc[2][0]); acc[2][1] = fmaf(a.z, w.y, acc[2][1]);
            acc[2][2] = fmaf(a.z, w.z, acc[2][2]); acc[2][3] = fmaf(a.z, w.w, acc[2][3]);
            acc[3][0] = fmaf(a.w, w.x, acc[3][0]); acc[3][1] = fmaf(a.w, w.y, acc[3][1]);
            acc[3][2] = fmaf(a.w, w.z, acc[3][2]); acc[3][3] = fmaf(a.w, w.w, acc[3][3]);
        }
        __syncthreads();
    }
    // layer-1 epilogue: bias + relu -> hT[c][r] in xs
#pragma unroll
    for (int jj = 0; jj < 4; ++jj) {
        float b = b0[tc * 4 + jj];
        float4 v;
        v.x = fmaxf(acc[0][jj] + b, 0.f);
        v.y = fmaxf(acc[1][jj] + b, 0.f);
        v.z = fmaxf(acc[2][jj] + b, 0.f);
        v.w = fmaxf(acc[3][jj] + b, 0.f);
        *(float4*)(xs + (tc * 4 + jj) * LDW + tr * 4) = v;
    }
#pragma unroll
    for (int j = 0; j < 4; ++j) {  // stage W1 [k][c]
        int l = tid + 256 * j;
        int kk = l >> 4, cq = l & 15;
        *(float4*)(ws + kk * LDW + cq * 4) = *(const float4*)(W1 + (size_t)kk * 64 + cq * 4);
    }
    float acc2[4][4];
#pragma unroll
    for (int i = 0; i < 4; ++i)
#pragma unroll
        for (int j = 0; j < 4; ++j) acc2[i][j] = 0.f;
    __syncthreads();
#pragma unroll 4
    for (int k = 0; k < 64; ++k) {
        float4 a = *(const float4*)(xs + k * LDW + tr * 4);
        float4 w = *(const float4*)(ws + k * LDW + tc * 4);
        acc2[0][0] = fmaf(a.x, w.x, acc2[0][0]); acc2[0][1] = fmaf(a.x, w.y, acc2[0][1]);
        acc2[0][2] = fmaf(a.x, w.z, acc2[0][2]); acc2[0][3] = fmaf(a.x, w.w, acc2[0][3]);
        acc2[1][0] = fmaf(a.y, w.x, acc2[1][0]); acc2[1][1] = fmaf(a.y, w.y, acc2[1][1]);
        acc2[1][2] = fmaf(a.y, w.z, acc2[1][2]); acc2[1][3] = fmaf(a.y, w.w, acc2[1][3]);
        acc2[2][0] = fmaf(a.z, w.x, acc2[2][0]); acc2[2][1] = fmaf(a.z, w.y, acc2[2][1]);
        acc2[2][2] = fmaf(a.z, w.z, acc2[2][2]); acc2[2][3] = fmaf(a.z, w.w, acc2[2][3]);
        acc2[3][0] = fmaf(a.w, w.x, acc2[3][0]); acc2[3][1] = fmaf(a.w, w.y, acc2[3][1]);
        acc2[3][2] = fmaf(a.w, w.z, acc2[3][2]); acc2[3][3] = fmaf(a.w, w.w, acc2[3][3]);
    }
    float bv0 = b1[tc * 4 + 0], bv1 = b1[tc * 4 + 1], bv2 = b1[tc * 4 + 2], bv3 = b1[tc * 4 + 3];
#pragma unroll
    for (int i = 0; i < 4; ++i) {
        int gr = rbase + tr * 4 + i;
        if (gr < N) {
            float4 o = make_float4(acc2[i][0] + bv0, acc2[i][1] + bv1, acc2[i][2] + bv2, acc2[i][3] + bv3);
            *(float4*)(h + (size_t)gr * 64 + tc * 4) = o;
        }
    }
}

// ---- one wave per destination node, lane = feature; pure gather, no atomics ----
__global__ __launch_bounds__(256) void k_prop(const int2* __restrict__ srcw,
                                              const int* __restrict__ rowp, const int* __restrict__ cnt,
                                              const float* __restrict__ dinv,
                                              const float* __restrict__ zin, const float* __restrict__ h,
                                              float* __restrict__ zout, int N) {
    int wid = (blockIdx.x << 2) | (threadIdx.x >> 6);
    int d = __builtin_amdgcn_readfirstlane(wid);  // force wave-uniform -> scalar loads for edges
    if (d >= N) return;
    int lane = threadIdx.x & 63;
    size_t dbase = (size_t)d * 64 + lane;
    float di = dinv[d];
    float acc = di * di * zin[dbase];  // analytic self-loop
    int beg = rowp[d], num = cnt[d];
    int e = beg, end = beg + num;
    for (; e + 4 <= end; e += 4) {
        int2 p0 = srcw[e + 0], p1 = srcw[e + 1], p2 = srcw[e + 2], p3 = srcw[e + 3];
        float z0 = zin[(size_t)p0.x * 64 + lane];
        float z1 = zin[(size_t)p1.x * 64 + lane];
        float z2 = zin[(size_t)p2.x * 64 + lane];
        float z3 = zin[(size_t)p3.x * 64 + lane];
        acc = fmaf(__int_as_float(p0.y), z0, acc);
        acc = fmaf(__int_as_float(p1.y), z1, acc);
        acc = fmaf(__int_as_float(p2.y), z2, acc);
        acc = fmaf(__int_as_float(p3.y), z3, acc);
    }
    for (; e < end; ++e) {
        int2 p = srcw[e];
        acc = fmaf(__int_as_float(p.y), zin[(size_t)p.x * 64 + lane], acc);
    }
    zout[dbase] = 0.9f * acc + 0.1f * h[dbase];
}

extern "C" void kernel_launch(void* const* d_in, const int* in_sizes, int n_in,
                              void* d_out, int out_size, void* d_ws, size_t ws_size,
                              hipStream_t stream) {
    const float* x  = (const float*)d_in[0];
    const int*   ei = (const int*)d_in[1];
    const float* ew = (const float*)d_in[2];
    const float* W0 = (const float*)d_in[3];
    const float* b0 = (const float*)d_in[4];
    const float* W1 = (const float*)d_in[5];
    const float* b1 = (const float*)d_in[6];
    int N = in_sizes[0] / 512;
    int E = in_sizes[2];
    const int* row = ei;
    const int* col = ei + E;

    char* p = (char*)d_ws;
    auto alloc = [&](size_t bytes) -> char* {
        char* r = p;
        p += (bytes + 255) & ~(size_t)255;
        return r;
    };
    float* h    = (float*)alloc((size_t)N * 64 * 4);  // 25.6 MB
    float* zA   = (float*)alloc((size_t)N * 64 * 4);  // 25.6 MB
    int2*  srcw = (int2*)alloc((size_t)E * 8);        // 25.6 MB
    float* dinv = (float*)alloc((size_t)N * 4);
    int* cnt    = (int*)alloc((size_t)N * 4);
    int* rowp   = (int*)alloc((size_t)N * 4);
    int* cursor = (int*)alloc((size_t)N * 4);
    int* csum   = (int*)alloc(256 * 4);

    hipMemsetAsync(cnt, 0, (size_t)N * 4, stream);
    hipMemsetAsync(cursor, 0, (size_t)N * 4, stream);

    int gN = (N + 255) / 256, gE = (E + 255) / 256;
    int NC = (N + 1023) / 1024;
    k_init_deg<<<gN, 256, 0, stream>>>(dinv, N);
    k_deg_cnt<<<gE, 256, 0, stream>>>(row, col, ew, dinv, cnt, E);
    k_rsqrt<<<gN, 256, 0, stream>>>(dinv, N);
    k_scanA<<<NC, 256, 0, stream>>>(cnt, csum, N);
    k_scanB<<<1, 256, 0, stream>>>(csum, NC);
    k_scanC<<<NC, 256, 0, stream>>>(cnt, csum, rowp, N);
    k_scatter<<<gE, 256, 0, stream>>>(row, col, ew, dinv, rowp, cursor, srcw, E);
    k_mlp<<<(N + 63) / 64, 256, 0, stream>>>(x, W0, b0, W1, b1, h, N);

    float* bufs[2] = { zA, (float*)d_out };  // odd iters -> zA, even -> d_out; iter 10 lands in d_out
    const float* zi = h;
    int gP = (N + 3) / 4;
    for (int it = 0; it < 10; ++it) {
        float* zo = bufs[it & 1];
        k_prop<<<gP, 256, 0, stream>>>(srcw, rowp, cnt, dinv, zi, h, zo, N);
        zi = zo;
    }
}